// Round 5
// baseline (182.813 us; speedup 1.0000x reference)
//
#include <hip/hip_runtime.h>
#include <hip/hip_bf16.h>
#include <stdint.h>

// ---------- types ----------
using frag8 = __attribute__((ext_vector_type(8))) short;   // 8 bf16 (4 VGPRs)
using f32x4 = __attribute__((ext_vector_type(4))) float;   // 4 fp32 acc

#define MFMA16 __builtin_amdgcn_mfma_f32_16x16x32_bf16

#if __has_builtin(__builtin_amdgcn_exp2f)
#define EXP2F(x) __builtin_amdgcn_exp2f(x)
#else
#define EXP2F(x) __expf((x) * 0.6931471805599453f)
#endif
#if __has_builtin(__builtin_amdgcn_rcpf)
#define RCPF(x) __builtin_amdgcn_rcpf(x)
#else
#define RCPF(x) (1.0f / (x))
#endif

// S' = (q.k)/8 * log2(e): folded into Q projection output
#define SCALE_Q 0.18033688011112042f

__device__ __forceinline__ short f2bf(float f) {
    union { float f; uint32_t u; } x; x.f = f;
    uint32_t r = x.u + 0x7fffu + ((x.u >> 16) & 1u);
    return (short)(r >> 16);
}
__device__ __forceinline__ float bf2f(short s) {
    union { uint32_t u; float f; } x; x.u = ((uint32_t)(uint16_t)s) << 16;
    return x.f;
}
__device__ __forceinline__ uint32_t pack2bf(float a, float b) {
    float2 t; t.x = a; t.y = b;
    __hip_bfloat162 h = __float22bfloat162_rn(t);
    union { __hip_bfloat162 h; uint32_t u; } c; c.h = h;
    return c.u;
}
__device__ __forceinline__ frag8 cvt8(float4 a, float4 b) {
    frag8 r;
    r[0] = f2bf(a.x); r[1] = f2bf(a.y); r[2] = f2bf(a.z); r[3] = f2bf(a.w);
    r[4] = f2bf(b.x); r[5] = f2bf(b.y); r[6] = f2bf(b.z); r[7] = f2bf(b.w);
    return r;
}
__device__ __forceinline__ frag8 addbf8(uint4 x, uint4 y) {
    frag8 r;
    const ushort* xs = (const ushort*)&x;
    const ushort* ys = (const ushort*)&y;
#pragma unroll
    for (int i = 0; i < 8; i++)
        r[i] = f2bf(bf2f((short)xs[i]) + bf2f((short)ys[i]));
    return r;
}

// ---------- K_compact: order-preserving unmasked-q index compaction ----------
__global__ __launch_bounds__(64) void k_compact(const int* __restrict__ mask,
                                                int* __restrict__ idx,
                                                int* __restrict__ nU) {
    const int b = blockIdx.x, ln = threadIdx.x;
    const int* m = mask + b * 2048;
    int* id = idx + b * 2048;
    int base = 0;
    for (int c = 0; c < 32; c++) {
        int i = c * 64 + ln;
        int mv = m[i];
        unsigned long long bal = __ballot(mv != 0);
        int rank = __popcll(bal & ((1ull << ln) - 1ull));
        if (mv) id[base + rank] = i;
        base += __popcll(bal);
    }
    if (ln == 0) nU[b] = base;
    int nUr = (base + 63) & ~63;
    for (int i = base + ln; i < nUr; i += 64) id[i] = 0;  // safe pad
}

// ---------- K_zero2: zero-fill both partial buffers ----------
__global__ __launch_bounds__(256) void k_zero2(uint4* __restrict__ a,
                                               uint4* __restrict__ b, int n16) {
    int i = blockIdx.x * 256 + threadIdx.x;
    if (i < n16) { uint4 z = {0, 0, 0, 0}; a[i] = z; b[i] = z; }
}

// ---------- K_psum: p0 += p1 (bf16, in-place) ----------
__global__ __launch_bounds__(256) void k_psum(short* __restrict__ p0,
                                              const short* __restrict__ p1, int n8) {
    int i = blockIdx.x * 256 + threadIdx.x;
    int st = gridDim.x * 256;
    for (; i < n8; i += st) {
        uint4 a = ((const uint4*)p0)[i];
        uint4 b = ((const uint4*)p1)[i];
        frag8 r = addbf8(a, b);
        ((uint4*)p0)[i] = *(uint4*)&r;
    }
}

// ---------- K_gather: q_c[bh][i][64] = q_s[bh][idx[b][i]][64] ----------
__global__ __launch_bounds__(256) void k_gather(const short* __restrict__ q_s,
                                                const int* __restrict__ idx,
                                                const int* __restrict__ nU,
                                                short* __restrict__ q_c) {
    const int bh = blockIdx.x, tile = blockIdx.y, b = bh >> 4;
    const int n = nU[b], nUr = (n + 63) & ~63;
    const int i = tile * 64 + (threadIdx.x >> 2);
    if (i >= nUr) return;
    const int src = idx[b * 2048 + i];
    const uint4* sp = (const uint4*)(q_s + ((size_t)bh * 2048 + src) * 64);
    uint4* dp = (uint4*)(q_c + ((size_t)bh * 2048 + i) * 64);
    const int c = threadIdx.x & 3;
    dp[c] = sp[c];
    dp[c + 4] = sp[c + 4];
}

// ---------- K_cvt_w: fp32 -> bf16 for the 4 weight matrices ----------
__global__ __launch_bounds__(256) void k_cvt_w(
    const float* __restrict__ s0, const float* __restrict__ s1,
    const float* __restrict__ s2, const float* __restrict__ s3,
    short* __restrict__ d0, short* __restrict__ d1,
    short* __restrict__ d2, short* __restrict__ d3) {
    const int W4 = 262144;                      // float4 per matrix
    int i = blockIdx.x * 256 + threadIdx.x;
    int st = gridDim.x * 256;
    for (; i < 4 * W4; i += st) {
        int seg = i / W4, j = i - seg * W4;
        const float* sp = seg == 0 ? s0 : seg == 1 ? s1 : seg == 2 ? s2 : s3;
        short* dp = seg == 0 ? d0 : seg == 1 ? d1 : seg == 2 ? d2 : d3;
        float4 v = ((const float4*)sp)[j];
        ushort4 o;
        o.x = (uint16_t)f2bf(v.x); o.y = (uint16_t)f2bf(v.y);
        o.z = (uint16_t)f2bf(v.z); o.w = (uint16_t)f2bf(v.w);
        ((ushort4*)dp)[j] = o;
    }
}

// ---------- swizzled staging: [64 rows][128B], XOR chunk ^= row&7 ----------
__device__ __forceinline__ void stage64x128(const short* __restrict__ g, int rs,
                                            short* lds, int tid) {
#pragma unroll
    for (int j = 0; j < 2; j++) {
        int chunk = j * 256 + tid;            // 0..511
        int row = chunk >> 3, c = chunk & 7;
        int sc = c ^ (row & 7);
        __builtin_amdgcn_global_load_lds(
            (const __attribute__((address_space(1))) uint32_t*)(g + (size_t)row * rs + sc * 8),
            (__attribute__((address_space(3))) uint32_t*)(lds + (j * 256 + (tid & 192)) * 8),
            16, 0, 0);
    }
}
// swizzled b128 read: logical (row, 16B-chunk cc)
__device__ __forceinline__ frag8 ldswz(const short* lds, int row, int cc) {
    return *(const frag8*)(lds + row * 64 + ((cc ^ (row & 7)) << 3));
}

// ---------- GEMM staging helpers (linear m97-style) ----------
__device__ __forceinline__ void stage_tiles(const short* __restrict__ As,
                                            const short* __restrict__ Bs,
                                            short* lA, short* lB,
                                            int w, int ln) {
#pragma unroll
    for (int j = 0; j < 2; j++) {
        int cb = (w * 2 + j) * 64;
        int c  = cb + ln;
        int row = c >> 2, c8 = c & 3;
        __builtin_amdgcn_global_load_lds(
            (const __attribute__((address_space(1))) uint32_t*)(As + row * 1024 + c8 * 8),
            (__attribute__((address_space(3))) uint32_t*)(lA + cb * 8), 16, 0, 0);
        __builtin_amdgcn_global_load_lds(
            (const __attribute__((address_space(1))) uint32_t*)(Bs + row * 1024 + c8 * 8),
            (__attribute__((address_space(3))) uint32_t*)(lB + cb * 8), 16, 0, 0);
    }
}
__device__ __forceinline__ void stage_b(const short* __restrict__ Bs,
                                        short* lB, int w, int ln) {
#pragma unroll
    for (int j = 0; j < 2; j++) {
        int cb = (w * 2 + j) * 64;
        int c  = cb + ln;
        int row = c >> 2, c8 = c & 3;
        __builtin_amdgcn_global_load_lds(
            (const __attribute__((address_space(1))) uint32_t*)(Bs + row * 1024 + c8 * 8),
            (__attribute__((address_space(3))) uint32_t*)(lB + cb * 8), 16, 0, 0);
    }
}

// ---------- K1: fused QKV projection, A reg-staged from fp32 ----------
__global__ __launch_bounds__(256) void k_proj3(
    const float* __restrict__ A0, const float* __restrict__ A1, const float* __restrict__ A2,
    const short* __restrict__ B0, const short* __restrict__ B1, const short* __restrict__ B2,
    const float* __restrict__ bias0, const float* __restrict__ bias1, const float* __restrict__ bias2,
    short* __restrict__ dst0, short* __restrict__ dst1, short* __restrict__ dst2) {
    __shared__ short lA[2][4096];
    __shared__ short lB[2][4096];
    const int z = blockIdx.z;
    const float* A  = z == 0 ? A0 : z == 1 ? A1 : A2;
    const short* Bt = z == 0 ? B0 : z == 1 ? B1 : B2;
    const float* bias = z == 0 ? bias0 : z == 1 ? bias1 : bias2;
    short* dst = z == 0 ? dst0 : z == 1 ? dst1 : dst2;
    const float scale = z == 0 ? SCALE_Q : 1.0f;

    const int tid = threadIdx.x, w = tid >> 6, ln = tid & 63;
    const int wm = w >> 1, wn = w & 1, r16 = ln & 15, g = ln >> 4;
    const int tn = blockIdx.x * 128, tm = blockIdx.y * 128;
    const float* Ab = A + (size_t)tm * 1024;
    const short* Bb = Bt + (size_t)tn * 1024;

    const int cb0 = (w * 2 + 0) * 64 + ln, cb1 = (w * 2 + 1) * 64 + ln;
    const int rA0 = cb0 >> 2, cA0 = cb0 & 3, rA1 = cb1 >> 2, cA1 = cb1 & 3;

    float4 ra[4];
    f32x4 acc[4][4] = {};

    // prolog (ks = 0)
    {
        const float* a0 = Ab + (size_t)rA0 * 1024 + cA0 * 8;
        ra[0] = *(const float4*)a0; ra[1] = *(const float4*)(a0 + 4);
        const float* a1 = Ab + (size_t)rA1 * 1024 + cA1 * 8;
        ra[2] = *(const float4*)a1; ra[3] = *(const float4*)(a1 + 4);
    }
    stage_b(Bb, &lB[0][0], w, ln);
    *(frag8*)&lA[0][cb0 * 8] = cvt8(ra[0], ra[1]);
    *(frag8*)&lA[0][cb1 * 8] = cvt8(ra[2], ra[3]);

    int buf = 0;
    for (int ks = 0; ks < 32; ks++) {
        if (ks + 1 < 32) {  // issue next A loads early (global->reg)
            const float* a0 = Ab + (size_t)rA0 * 1024 + (ks + 1) * 32 + cA0 * 8;
            ra[0] = *(const float4*)a0; ra[1] = *(const float4*)(a0 + 4);
            const float* a1 = Ab + (size_t)rA1 * 1024 + (ks + 1) * 32 + cA1 * 8;
            ra[2] = *(const float4*)a1; ra[3] = *(const float4*)(a1 + 4);
        }
        __syncthreads();   // buf ready; all waves done reading buf^1
        if (ks + 1 < 32)
            stage_b(Bb + (ks + 1) * 32, &lB[buf ^ 1][0], w, ln);
        frag8 af[4], bg[4];
#pragma unroll
        for (int mf = 0; mf < 4; mf++)
            af[mf] = *(const frag8*)&lA[buf][(wm * 64 + mf * 16 + r16) * 32 + g * 8];
#pragma unroll
        for (int nf = 0; nf < 4; nf++)
            bg[nf] = *(const frag8*)&lB[buf][(wn * 64 + nf * 16 + r16) * 32 + g * 8];
#pragma unroll
        for (int mf = 0; mf < 4; mf++)
#pragma unroll
            for (int nf = 0; nf < 4; nf++)
                acc[mf][nf] = MFMA16(af[mf], bg[nf], acc[mf][nf], 0, 0, 0);
        if (ks + 1 < 32) {  // write next A tile (cvt from regs)
            *(frag8*)&lA[buf ^ 1][cb0 * 8] = cvt8(ra[0], ra[1]);
            *(frag8*)&lA[buf ^ 1][cb1 * 8] = cvt8(ra[2], ra[3]);
        }
        buf ^= 1;
    }
#pragma unroll
    for (int mf = 0; mf < 4; mf++)
#pragma unroll
        for (int nf = 0; nf < 4; nf++)
#pragma unroll
            for (int r = 0; r < 4; r++) {
                int m = tm + wm * 64 + mf * 16 + g * 4 + r;
                int n = tn + wn * 64 + nf * 16 + r16;
                float val = (acc[mf][nf][r] + bias[n]) * scale;
                int b = m >> 11, seq = m & 2047, h = n >> 6, d = n & 63;
                dst[((size_t)(b * 16 + h) * 2048 + seq) * 64 + d] = f2bf(val);
            }
}

// ---------- K2: stats + fused v-scale (compacted q sweep) ----------
__global__ __launch_bounds__(256, 4) void k_stats(const short* __restrict__ k_s,
                                                  const short* __restrict__ q_c,
                                                  const int* __restrict__ nU,
                                                  const short* __restrict__ v_s,
                                                  short* __restrict__ vhatT) {
    __shared__ short lQ[2][4096];
    __shared__ float lD[64];
    __shared__ short lT[64 * 70];               // v tile [k][d], row stride 70
    const int wg = blockIdx.x;
    const int lin = (wg & 7) * 128 + (wg >> 3); // XCD swizzle
    const int bh = lin >> 5, kt = lin & 31;
    const int b = bh >> 4;
    const int n = nU[b], nUr = (n + 63) & ~63;
    const int tid = threadIdx.x, w = tid >> 6, ln = tid & 63;
    const int r16 = ln & 15, g = ln >> 4;
    const int kbase = kt * 64 + w * 16;

    const short* kp = k_s + ((size_t)bh * 2048 + kbase) * 64;
    frag8 kf[2];
#pragma unroll
    for (int kk = 0; kk < 2; kk++)
        kf[kk] = *(const frag8*)(kp + r16 * 64 + kk * 32 + g * 8);

    const short* qsp = q_c + (size_t)bh * 2048 * 64;
    float dacc[4] = {};
    const f32x4 z4 = {0.f, 0.f, 0.f, 0.f};

    if (nUr > 0) {
        stage64x128(qsp, 64, &lQ[0][0], tid);
        int buf = 0;
        for (int qb = 0; qb < nUr; qb += 64) {
            __syncthreads();
            if (qb + 64 < nUr)
                stage64x128(qsp + (size_t)(qb + 64) * 64, 64, &lQ[buf ^ 1][0], tid);
            const short* Qc = &lQ[buf][0];
#pragma unroll
            for (int nf = 0; nf < 4; nf++) {
                float fm = (qb + nf * 16 + r16 < n) ? 1.0f : 0.0f;
                frag8 bq0 = ldswz(Qc, nf * 16 + r16, g);
                frag8 bq1 = ldswz(Qc, nf * 16 + r16, 4 + g);
                f32x4 s = MFMA16(kf[0], bq0, z4, 0, 0, 0);
                s = MFMA16(kf[1], bq1, s, 0, 0, 0);
#pragma unroll
                for (int r = 0; r < 4; r++)
                    dacc[r] += fm * EXP2F(s[r]);
            }
            buf ^= 1;
        }
    }
#pragma unroll
    for (int r = 0; r < 4; r++) {
        float v = dacc[r];
#pragma unroll
        for (int off = 1; off < 16; off <<= 1)
            v += __shfl_xor(v, off, 16);
        dacc[r] = v;
    }
    if (r16 == 0) {
#pragma unroll
        for (int r = 0; r < 4; r++)
            lD[w * 16 + g * 4 + r] = RCPF(dacc[r]);
    }
    // stage v tile [64k][64d] into lT (stride 70)
    const short* vrow = v_s + ((size_t)bh * 2048 + kt * 64) * 64;
#pragma unroll
    for (int i = 0; i < 4; i++) {
        int idx4 = i * 256 + tid;               // ushort4 units
        int row = idx4 >> 4, c4 = idx4 & 15;
        uint2 u = *(const uint2*)(vrow + (size_t)row * 64 + c4 * 4);
        *(uint32_t*)&lT[row * 70 + c4 * 4]     = u.x;
        *(uint32_t*)&lT[row * 70 + c4 * 4 + 2] = u.y;
    }
    __syncthreads();
    // transposed write: vhatT[bh][d][kt*64 + kc*16 .. +16]
    {
        int d = tid >> 2, kc = tid & 3;
        short* dstp = vhatT + ((size_t)bh * 64 + d) * 2048 + kt * 64 + kc * 16;
        uint32_t wd[8];
#pragma unroll
        for (int j2 = 0; j2 < 8; j2++) {
            int k0 = kc * 16 + j2 * 2;
            float v0 = bf2f(lT[k0 * 70 + d]) * lD[k0];
            float v1 = bf2f(lT[(k0 + 1) * 70 + d]) * lD[k0 + 1];
            wd[j2] = pack2bf(v0, v1);
        }
        uint4 o0 = {wd[0], wd[1], wd[2], wd[3]};
        uint4 o1 = {wd[4], wd[5], wd[6], wd[7]};
        *(uint4*)dstp = o0;
        *((uint4*)dstp + 1) = o1;
    }
}

// ---------- K4: apply, SPLIT-2 over k; partials to p0/p1 ----------
__global__ __launch_bounds__(256, 4) void k_apply(const short* __restrict__ q_c,
                                                  const short* __restrict__ k_s,
                                                  const short* __restrict__ vhatT,
                                                  const int* __restrict__ idx,
                                                  const int* __restrict__ nU,
                                                  short* __restrict__ p0,
                                                  short* __restrict__ p1) {
    __shared__ short lK[2][4096];
    __shared__ short lV[2][4096];
    __shared__ short lP[64 * 64];               // P[q][k] bf16, chunk-XOR swizzled
    const int wg = blockIdx.x;
    const int lin = (wg & 7) * 256 + (wg >> 3); // XCD swizzle over 2048
    const int bh = lin >> 6, rem = lin & 63, qt = rem >> 1, sp = rem & 1;
    const int b = bh >> 4, h = bh & 15;
    const int n = nU[b];
    if (qt * 64 >= n) return;                   // uniform early exit
    const int tid = threadIdx.x, w = tid >> 6, ln = tid & 63;
    const int r16 = ln & 15, g = ln >> 4;

    const short* qp = q_c + ((size_t)bh * 2048 + qt * 64 + w * 16) * 64;
    frag8 qf[2];
#pragma unroll
    for (int kk = 0; kk < 2; kk++)
        qf[kk] = *(const frag8*)(qp + r16 * 64 + kk * 32 + g * 8);

    const short* kp = k_s + ((size_t)bh * 2048 + sp * 1024) * 64;
    const short* vp = vhatT + (size_t)bh * 64 * 2048 + sp * 1024;

    f32x4 oacc[4] = {};
    const f32x4 z4 = {0.f, 0.f, 0.f, 0.f};
    const int prow = w * 16 + r16, rx = prow & 7;

    stage64x128(kp, 64, &lK[0][0], tid);
    stage64x128(vp, 2048, &lV[0][0], tid);
    int buf = 0;
    for (int kb = 0; kb < 1024; kb += 64) {
        __syncthreads();
        if (kb + 64 < 1024) {
            stage64x128(kp + (size_t)(kb + 64) * 64, 64, &lK[buf ^ 1][0], tid);
            stage64x128(vp + kb + 64, 2048, &lV[buf ^ 1][0], tid);
        }
        const short* Kc = &lK[buf][0];
        const short* Vc = &lV[buf][0];
        // hoist V fragment reads (independent of QK^T chain)
        frag8 vb[4][2];
#pragma unroll
        for (int nf = 0; nf < 4; nf++)
#pragma unroll
            for (int kk = 0; kk < 2; kk++)
                vb[nf][kk] = ldswz(Vc, nf * 16 + r16, kk * 4 + g);
        // S^T (64k x 16q per wave) -> exp2 -> P[q][k]
#pragma unroll
        for (int mf2 = 0; mf2 < 4; mf2++) {
            f32x4 s = z4;
#pragma unroll
            for (int kk = 0; kk < 2; kk++)
                s = MFMA16(ldswz(Kc, mf2 * 16 + r16, kk * 4 + g), qf[kk], s, 0, 0, 0);
            float e0 = EXP2F(s[0]), e1 = EXP2F(s[1]);
            float e2 = EXP2F(s[2]), e3 = EXP2F(s[3]);
            uint2 pk;
            pk.x = pack2bf(e0, e1);
            pk.y = pack2bf(e2, e3);
            int o = mf2 * 32 + g * 8;           // byte offset in 128B P row
            int addr = prow * 128 + (((o >> 4) ^ rx) << 4) + (o & 15);
            *(uint2*)((char*)lP + addr) = pk;
        }
        // PV: oacc[d] += P[q][k] * vhat[d][k]   (same-wave P RAW: DS in-order)
        frag8 pa[2];
#pragma unroll
        for (int kk = 0; kk < 2; kk++)
            pa[kk] = *(const frag8*)((char*)lP + prow * 128 + (((kk * 4 + g) ^ rx) << 4));
#pragma unroll
        for (int nf = 0; nf < 4; nf++)
#pragma unroll
            for (int kk = 0; kk < 2; kk++)
                oacc[nf] = MFMA16(pa[kk], vb[nf][kk], oacc[nf], 0, 0, 0);
        buf ^= 1;
    }
    // epilogue: scatter unmasked rows to the split's partial buffer
    short* op = sp ? p1 : p0;
#pragma unroll
    for (int r = 0; r < 4; r++) {
        int lq = qt * 64 + w * 16 + g * 4 + r;
        if (lq < n) {
            int qg = idx[b * 2048 + lq];
#pragma unroll
            for (int nf = 0; nf < 4; nf++) {
                int d = nf * 16 + r16;
                op[((size_t)(b * 2048 + qg)) * 1024 + h * 64 + d] = f2bf(oacc[nf][r]);
            }
        }
    }
}

// ---------- K5: out = attn @ Wo^T + b_O + Q ----------
__global__ __launch_bounds__(256) void k_final(const short* __restrict__ A,
                                               const short* __restrict__ Bt,
                                               const float* __restrict__ bias,
                                               const float* __restrict__ Qres,
                                               float* __restrict__ out) {
    __shared__ short lA[2][4096];
    __shared__ short lB[2][4096];
    const int tid = threadIdx.x, w = tid >> 6, ln = tid & 63;
    const int wm = w >> 1, wn = w & 1, r16 = ln & 15, g = ln >> 4;
    const int tn = blockIdx.x * 128, tm = blockIdx.y * 128;
    const short* Ab = A + (size_t)tm * 1024;
    const short* Bb = Bt + (size_t)tn * 1024;

    f32x4 acc[4][4] = {};
    stage_tiles(Ab, Bb, &lA[0][0], &lB[0][0], w, ln);
    int buf = 0;
    for (int ks = 0; ks < 32; ks++) {
        __syncthreads();
        if (ks + 1 < 32)
            stage_tiles(Ab + (ks + 1) * 32, Bb + (ks + 1) * 32,
                        &lA[buf ^ 1][0], &lB[buf ^ 1][0], w, ln);
        frag8 af[4], bg[4];
#pragma unroll
        for (int mf = 0; mf < 4; mf++)
            af[mf] = *(const frag8*)&lA[buf][(wm * 64 + mf * 16 + r16) * 32 + g * 8];
#pragma unroll
        for (int nf = 0; nf < 4; nf++)
            bg[nf] = *(const frag8*)&lB[buf][(wn * 64 + nf * 16 + r16) * 32 + g * 8];
#pragma unroll
        for (int mf = 0; mf < 4; mf++)
#pragma unroll
            for (int nf = 0; nf < 4; nf++)
                acc[mf][nf] = MFMA16(af[mf], bg[nf], acc[mf][nf], 0, 0, 0);
        buf ^= 1;
    }
#pragma unroll
    for (int mf = 0; mf < 4; mf++)
#pragma unroll
        for (int nf = 0; nf < 4; nf++)
#pragma unroll
            for (int r = 0; r < 4; r++) {
                int m = tm + wm * 64 + mf * 16 + g * 4 + r;
                int n = tn + wn * 64 + nf * 16 + r16;
                float val = acc[mf][nf][r] + bias[n] + Qres[(size_t)m * 1024 + n];
                out[(size_t)m * 1024 + n] = val;
            }
}

// ---------- launch ----------
extern "C" void kernel_launch(void* const* d_in, const int* in_sizes, int n_in,
                              void* d_out, int out_size, void* d_ws, size_t ws_size,
                              hipStream_t stream) {
    (void)in_sizes; (void)n_in; (void)out_size; (void)ws_size;
    const float* Qf  = (const float*)d_in[0];
    const float* Kf  = (const float*)d_in[1];
    const float* Vf  = (const float*)d_in[2];
    const int*   msk = (const int*)d_in[3];
    const float* WQ  = (const float*)d_in[4];
    const float* bQ  = (const float*)d_in[5];
    const float* WK  = (const float*)d_in[6];
    const float* bK  = (const float*)d_in[7];
    const float* WV  = (const float*)d_in[8];
    const float* bV  = (const float*)d_in[9];
    const float* WO  = (const float*)d_in[10];
    const float* bO  = (const float*)d_in[11];
    float* out = (float*)d_out;

    char* p = (char*)d_ws;
    const size_t SZ_ACT = (size_t)4096 * 1024 * 2;  // 8 MB bf16
    const size_t SZ_W   = (size_t)1024 * 1024 * 2;  // 2 MB
    short* q_s   = (short*)p; p += SZ_ACT;
    short* k_s   = (short*)p; p += SZ_ACT;
    short* v_s   = (short*)p; p += SZ_ACT;
    short* vhatT = (short*)p; p += SZ_ACT;
    short* p0    = (short*)p; p += SZ_ACT;         // attn partial 0 / final attn
    short* q_c   = (short*)p; p += SZ_ACT;
    short* Wqb = (short*)p; p += SZ_W;
    short* Wkb = (short*)p; p += SZ_W;
    short* Wvb = (short*)p; p += SZ_W;
    short* Wob = (short*)p; p += SZ_W;
    int* idx = (int*)p; p += (size_t)2 * 2048 * 4;
    int* nU  = (int*)p; p += 256;
    short* p1 = v_s;                                // dead after k_stats

    // compaction of unmasked q indices (mask-only dependency)
    k_compact<<<2, 64, 0, stream>>>(msk, idx, nU);

    // weight converts (activations are consumed fp32 by k_proj3 directly)
    k_cvt_w<<<1024, 256, 0, stream>>>(WQ, WK, WV, WO, Wqb, Wkb, Wvb, Wob);

    // fused projections (z: 0=Q scaled, 1=K, 2=V); A reg-staged from fp32
    k_proj3<<<dim3(8, 32, 3), 256, 0, stream>>>(Qf, Kf, Vf, Wqb, Wkb, Wvb,
                                                bQ, bK, bV, q_s, k_s, v_s);

    // gather compacted Q rows
    k_gather<<<dim3(32, 32), 256, 0, stream>>>(q_s, idx, nU, q_c);

    // column softmax denominators + fused v-scale/transpose
    k_stats<<<1024, 256, 0, stream>>>(k_s, q_c, nU, v_s, vhatT);

    // zero both partial buffers (masked rows must be 0); v_s dead now
    k_zero2<<<2048, 256, 0, stream>>>((uint4*)p0, (uint4*)p1, 524288);

    // attention apply, split-2 over k
    k_apply<<<2048, 256, 0, stream>>>(q_c, k_s, vhatT, idx, nU, p0, p1);

    // sum partials into p0
    k_psum<<<2048, 256, 0, stream>>>(p0, p1, 524288);

    // output projection + bias + residual
    k_final<<<dim3(8, 32), 256, 0, stream>>>(p0, Wob, bO, Qf, out);
}

// Round 6
// 161.475 us; speedup vs baseline: 1.1321x; 1.1321x over previous
//
#include <hip/hip_runtime.h>
#include <hip/hip_bf16.h>
#include <stdint.h>

// ---------- types ----------
using frag8 = __attribute__((ext_vector_type(8))) short;   // 8 bf16 (4 VGPRs)
using f32x4 = __attribute__((ext_vector_type(4))) float;   // 4 fp32 acc

#define MFMA16 __builtin_amdgcn_mfma_f32_16x16x32_bf16

#if __has_builtin(__builtin_amdgcn_exp2f)
#define EXP2F(x) __builtin_amdgcn_exp2f(x)
#else
#define EXP2F(x) __expf((x) * 0.6931471805599453f)
#endif
#if __has_builtin(__builtin_amdgcn_rcpf)
#define RCPF(x) __builtin_amdgcn_rcpf(x)
#else
#define RCPF(x) (1.0f / (x))
#endif

// S' = (q.k)/8 * log2(e): folded into Q projection output
#define SCALE_Q 0.18033688011112042f

__device__ __forceinline__ short f2bf(float f) {
    union { float f; uint32_t u; } x; x.f = f;
    uint32_t r = x.u + 0x7fffu + ((x.u >> 16) & 1u);
    return (short)(r >> 16);
}
__device__ __forceinline__ float bf2f(short s) {
    union { uint32_t u; float f; } x; x.u = ((uint32_t)(uint16_t)s) << 16;
    return x.f;
}
__device__ __forceinline__ uint32_t pack2bf(float a, float b) {
    float2 t; t.x = a; t.y = b;
    __hip_bfloat162 h = __float22bfloat162_rn(t);
    union { __hip_bfloat162 h; uint32_t u; } c; c.h = h;
    return c.u;
}
__device__ __forceinline__ frag8 cvt8(float4 a, float4 b) {
    frag8 r;
    r[0] = f2bf(a.x); r[1] = f2bf(a.y); r[2] = f2bf(a.z); r[3] = f2bf(a.w);
    r[4] = f2bf(b.x); r[5] = f2bf(b.y); r[6] = f2bf(b.z); r[7] = f2bf(b.w);
    return r;
}
__device__ __forceinline__ frag8 addbf8(uint4 x, uint4 y) {
    frag8 r;
    const ushort* xs = (const ushort*)&x;
    const ushort* ys = (const ushort*)&y;
#pragma unroll
    for (int i = 0; i < 8; i++)
        r[i] = f2bf(bf2f((short)xs[i]) + bf2f((short)ys[i]));
    return r;
}

// ---------- K_compact: order-preserving unmasked-q index compaction ----------
__global__ __launch_bounds__(64) void k_compact(const int* __restrict__ mask,
                                                int* __restrict__ idx,
                                                int* __restrict__ nU) {
    const int b = blockIdx.x, ln = threadIdx.x;
    const int* m = mask + b * 2048;
    int* id = idx + b * 2048;
    int base = 0;
    for (int c = 0; c < 32; c++) {
        int i = c * 64 + ln;
        int mv = m[i];
        unsigned long long bal = __ballot(mv != 0);
        int rank = __popcll(bal & ((1ull << ln) - 1ull));
        if (mv) id[base + rank] = i;
        base += __popcll(bal);
    }
    if (ln == 0) nU[b] = base;
    int nUr = (base + 63) & ~63;
    for (int i = base + ln; i < nUr; i += 64) id[i] = 0;  // safe pad
}

// ---------- K_zero2: zero-fill both partial buffers ----------
__global__ __launch_bounds__(256) void k_zero2(uint4* __restrict__ a,
                                               uint4* __restrict__ b, int n16) {
    int i = blockIdx.x * 256 + threadIdx.x;
    if (i < n16) { uint4 z = {0, 0, 0, 0}; a[i] = z; b[i] = z; }
}

// ---------- K_psum: p0 += p1 (bf16, in-place) ----------
__global__ __launch_bounds__(256) void k_psum(short* __restrict__ p0,
                                              const short* __restrict__ p1, int n8) {
    int i = blockIdx.x * 256 + threadIdx.x;
    int st = gridDim.x * 256;
    for (; i < n8; i += st) {
        uint4 a = ((const uint4*)p0)[i];
        uint4 b = ((const uint4*)p1)[i];
        frag8 r = addbf8(a, b);
        ((uint4*)p0)[i] = *(uint4*)&r;
    }
}

// ---------- K_gather: q_c[bh][i][64] = q_s[bh][idx[b][i]][64] ----------
__global__ __launch_bounds__(256) void k_gather(const short* __restrict__ q_s,
                                                const int* __restrict__ idx,
                                                const int* __restrict__ nU,
                                                short* __restrict__ q_c) {
    const int bh = blockIdx.x, tile = blockIdx.y, b = bh >> 4;
    const int n = nU[b], nUr = (n + 63) & ~63;
    const int i = tile * 64 + (threadIdx.x >> 2);
    if (i >= nUr) return;
    const int src = idx[b * 2048 + i];
    const uint4* sp = (const uint4*)(q_s + ((size_t)bh * 2048 + src) * 64);
    uint4* dp = (uint4*)(q_c + ((size_t)bh * 2048 + i) * 64);
    const int c = threadIdx.x & 3;
    dp[c] = sp[c];
    dp[c + 4] = sp[c + 4];
}

// ---------- K_cvt_w: fp32 -> bf16 for the 4 weight matrices ----------
__global__ __launch_bounds__(256) void k_cvt_w(
    const float* __restrict__ s0, const float* __restrict__ s1,
    const float* __restrict__ s2, const float* __restrict__ s3,
    short* __restrict__ d0, short* __restrict__ d1,
    short* __restrict__ d2, short* __restrict__ d3) {
    const int W4 = 262144;                      // float4 per matrix
    int i = blockIdx.x * 256 + threadIdx.x;
    int st = gridDim.x * 256;
    for (; i < 4 * W4; i += st) {
        int seg = i / W4, j = i - seg * W4;
        const float* sp = seg == 0 ? s0 : seg == 1 ? s1 : seg == 2 ? s2 : s3;
        short* dp = seg == 0 ? d0 : seg == 1 ? d1 : seg == 2 ? d2 : d3;
        float4 v = ((const float4*)sp)[j];
        ushort4 o;
        o.x = (uint16_t)f2bf(v.x); o.y = (uint16_t)f2bf(v.y);
        o.z = (uint16_t)f2bf(v.z); o.w = (uint16_t)f2bf(v.w);
        ((ushort4*)dp)[j] = o;
    }
}

// ---------- swizzled staging: [64 rows][128B], XOR chunk ^= row&7 ----------
__device__ __forceinline__ void stage64x128(const short* __restrict__ g, int rs,
                                            short* lds, int tid) {
#pragma unroll
    for (int j = 0; j < 2; j++) {
        int chunk = j * 256 + tid;            // 0..511
        int row = chunk >> 3, c = chunk & 7;
        int sc = c ^ (row & 7);
        __builtin_amdgcn_global_load_lds(
            (const __attribute__((address_space(1))) uint32_t*)(g + (size_t)row * rs + sc * 8),
            (__attribute__((address_space(3))) uint32_t*)(lds + (j * 256 + (tid & 192)) * 8),
            16, 0, 0);
    }
}
// swizzled b128 read: logical (row, 16B-chunk cc)
__device__ __forceinline__ frag8 ldswz(const short* lds, int row, int cc) {
    return *(const frag8*)(lds + row * 64 + ((cc ^ (row & 7)) << 3));
}

// ---------- GEMM staging helpers (linear m97-style) ----------
__device__ __forceinline__ void stage_tiles(const short* __restrict__ As,
                                            const short* __restrict__ Bs,
                                            short* lA, short* lB,
                                            int w, int ln) {
#pragma unroll
    for (int j = 0; j < 2; j++) {
        int cb = (w * 2 + j) * 64;
        int c  = cb + ln;
        int row = c >> 2, c8 = c & 3;
        __builtin_amdgcn_global_load_lds(
            (const __attribute__((address_space(1))) uint32_t*)(As + row * 1024 + c8 * 8),
            (__attribute__((address_space(3))) uint32_t*)(lA + cb * 8), 16, 0, 0);
        __builtin_amdgcn_global_load_lds(
            (const __attribute__((address_space(1))) uint32_t*)(Bs + row * 1024 + c8 * 8),
            (__attribute__((address_space(3))) uint32_t*)(lB + cb * 8), 16, 0, 0);
    }
}
__device__ __forceinline__ void stage_b(const short* __restrict__ Bs,
                                        short* lB, int w, int ln) {
#pragma unroll
    for (int j = 0; j < 2; j++) {
        int cb = (w * 2 + j) * 64;
        int c  = cb + ln;
        int row = c >> 2, c8 = c & 3;
        __builtin_amdgcn_global_load_lds(
            (const __attribute__((address_space(1))) uint32_t*)(Bs + row * 1024 + c8 * 8),
            (__attribute__((address_space(3))) uint32_t*)(lB + cb * 8), 16, 0, 0);
    }
}

// ---------- K1: fused QKV projection, A reg-staged from fp32 ----------
// grid flat 768; wg%8 == tm%8 so all 8 tn-blocks of a tm share one XCD (A L2 reuse)
__global__ __launch_bounds__(256) void k_proj3(
    const float* __restrict__ A0, const float* __restrict__ A1, const float* __restrict__ A2,
    const short* __restrict__ B0, const short* __restrict__ B1, const short* __restrict__ B2,
    const float* __restrict__ bias0, const float* __restrict__ bias1, const float* __restrict__ bias2,
    short* __restrict__ dst0, short* __restrict__ dst1, short* __restrict__ dst2) {
    __shared__ short lA[2][4096];
    __shared__ short lB[2][4096];
    const int wg = blockIdx.x;
    const int tmlow = wg & 7, tnb = (wg >> 3) & 7, rest = wg >> 6;
    const int tmh = rest & 3, z = rest >> 2;    // z 0..2
    const int tmb = tmlow | (tmh << 3);         // 0..31
    const float* A  = z == 0 ? A0 : z == 1 ? A1 : A2;
    const short* Bt = z == 0 ? B0 : z == 1 ? B1 : B2;
    const float* bias = z == 0 ? bias0 : z == 1 ? bias1 : bias2;
    short* dst = z == 0 ? dst0 : z == 1 ? dst1 : dst2;
    const float scale = z == 0 ? SCALE_Q : 1.0f;

    const int tid = threadIdx.x, w = tid >> 6, ln = tid & 63;
    const int wm = w >> 1, wn = w & 1, r16 = ln & 15, g = ln >> 4;
    const int tn = tnb * 128, tm = tmb * 128;
    const float* Ab = A + (size_t)tm * 1024;
    const short* Bb = Bt + (size_t)tn * 1024;

    const int cb0 = (w * 2 + 0) * 64 + ln, cb1 = (w * 2 + 1) * 64 + ln;
    const int rA0 = cb0 >> 2, cA0 = cb0 & 3, rA1 = cb1 >> 2, cA1 = cb1 & 3;

    float4 ra[4];
    f32x4 acc[4][4] = {};

    {
        const float* a0 = Ab + (size_t)rA0 * 1024 + cA0 * 8;
        ra[0] = *(const float4*)a0; ra[1] = *(const float4*)(a0 + 4);
        const float* a1 = Ab + (size_t)rA1 * 1024 + cA1 * 8;
        ra[2] = *(const float4*)a1; ra[3] = *(const float4*)(a1 + 4);
    }
    stage_b(Bb, &lB[0][0], w, ln);
    *(frag8*)&lA[0][cb0 * 8] = cvt8(ra[0], ra[1]);
    *(frag8*)&lA[0][cb1 * 8] = cvt8(ra[2], ra[3]);

    int buf = 0;
    for (int ks = 0; ks < 32; ks++) {
        if (ks + 1 < 32) {  // issue next A loads early (global->reg)
            const float* a0 = Ab + (size_t)rA0 * 1024 + (ks + 1) * 32 + cA0 * 8;
            ra[0] = *(const float4*)a0; ra[1] = *(const float4*)(a0 + 4);
            const float* a1 = Ab + (size_t)rA1 * 1024 + (ks + 1) * 32 + cA1 * 8;
            ra[2] = *(const float4*)a1; ra[3] = *(const float4*)(a1 + 4);
        }
        __syncthreads();
        if (ks + 1 < 32)
            stage_b(Bb + (ks + 1) * 32, &lB[buf ^ 1][0], w, ln);
        frag8 af[4], bg[4];
#pragma unroll
        for (int mf = 0; mf < 4; mf++)
            af[mf] = *(const frag8*)&lA[buf][(wm * 64 + mf * 16 + r16) * 32 + g * 8];
#pragma unroll
        for (int nf = 0; nf < 4; nf++)
            bg[nf] = *(const frag8*)&lB[buf][(wn * 64 + nf * 16 + r16) * 32 + g * 8];
#pragma unroll
        for (int mf = 0; mf < 4; mf++)
#pragma unroll
            for (int nf = 0; nf < 4; nf++)
                acc[mf][nf] = MFMA16(af[mf], bg[nf], acc[mf][nf], 0, 0, 0);
        if (ks + 1 < 32) {
            *(frag8*)&lA[buf ^ 1][cb0 * 8] = cvt8(ra[0], ra[1]);
            *(frag8*)&lA[buf ^ 1][cb1 * 8] = cvt8(ra[2], ra[3]);
        }
        buf ^= 1;
    }
#pragma unroll
    for (int mf = 0; mf < 4; mf++)
#pragma unroll
        for (int nf = 0; nf < 4; nf++)
#pragma unroll
            for (int r = 0; r < 4; r++) {
                int m = tm + wm * 64 + mf * 16 + g * 4 + r;
                int n = tn + wn * 64 + nf * 16 + r16;
                float val = (acc[mf][nf][r] + bias[n]) * scale;
                int b = m >> 11, seq = m & 2047, h = n >> 6, d = n & 63;
                dst[((size_t)(b * 16 + h) * 2048 + seq) * 64 + d] = f2bf(val);
            }
}

// ---------- K2: stats + fused v-scale; wave owns 32 k (128 k / block) ----------
__global__ __launch_bounds__(256, 3) void k_stats(const short* __restrict__ k_s,
                                                  const short* __restrict__ q_c,
                                                  const int* __restrict__ nU,
                                                  const short* __restrict__ v_s,
                                                  short* __restrict__ vhatT) {
    __shared__ short lQ[2][4096];
    __shared__ float lD[128];
    __shared__ short lT[128 * 70];              // v tile [k][d], row stride 70
    const int wg = blockIdx.x;                  // 512 blocks
    const int x = wg & 7, r2 = wg >> 3;
    const int kt = r2 & 15;                     // 16 kt tiles of 128 k
    const int bh = x + 8 * (r2 >> 4);           // bh-grouped per XCD
    const int b = bh >> 4;
    const int n = nU[b], nUr = (n + 63) & ~63;
    const int tid = threadIdx.x, w = tid >> 6, ln = tid & 63;
    const int r16 = ln & 15, g = ln >> 4;
    const int kbase = kt * 128 + w * 32;

    const short* kp = k_s + ((size_t)bh * 2048 + kbase) * 64;
    frag8 kf[2][2];
#pragma unroll
    for (int mfk = 0; mfk < 2; mfk++)
#pragma unroll
        for (int kk = 0; kk < 2; kk++)
            kf[mfk][kk] = *(const frag8*)(kp + (mfk * 16 + r16) * 64 + kk * 32 + g * 8);

    const short* qsp = q_c + (size_t)bh * 2048 * 64;
    float dacc[2][4] = {};
    const f32x4 z4 = {0.f, 0.f, 0.f, 0.f};

    if (nUr > 0) {
        stage64x128(qsp, 64, &lQ[0][0], tid);
        int buf = 0;
        for (int qb = 0; qb < nUr; qb += 64) {
            __syncthreads();
            if (qb + 64 < nUr)
                stage64x128(qsp + (size_t)(qb + 64) * 64, 64, &lQ[buf ^ 1][0], tid);
            const short* Qc = &lQ[buf][0];
#pragma unroll
            for (int nf = 0; nf < 4; nf++) {
                float fm = (qb + nf * 16 + r16 < n) ? 1.0f : 0.0f;
                frag8 bq0 = ldswz(Qc, nf * 16 + r16, g);
                frag8 bq1 = ldswz(Qc, nf * 16 + r16, 4 + g);
#pragma unroll
                for (int mfk = 0; mfk < 2; mfk++) {
                    f32x4 s = MFMA16(kf[mfk][0], bq0, z4, 0, 0, 0);
                    s = MFMA16(kf[mfk][1], bq1, s, 0, 0, 0);
#pragma unroll
                    for (int r = 0; r < 4; r++)
                        dacc[mfk][r] += fm * EXP2F(s[r]);
                }
            }
            buf ^= 1;
        }
    }
#pragma unroll
    for (int mfk = 0; mfk < 2; mfk++)
#pragma unroll
        for (int r = 0; r < 4; r++) {
            float v = dacc[mfk][r];
#pragma unroll
            for (int off = 1; off < 16; off <<= 1)
                v += __shfl_xor(v, off, 16);
            dacc[mfk][r] = v;
        }
    if (r16 == 0) {
#pragma unroll
        for (int mfk = 0; mfk < 2; mfk++)
#pragma unroll
            for (int r = 0; r < 4; r++)
                lD[w * 32 + mfk * 16 + g * 4 + r] = RCPF(dacc[mfk][r]);
    }
    // stage v tile [128 k][64 d] into lT (stride 70)
    const short* vrow = v_s + ((size_t)bh * 2048 + kt * 128) * 64;
#pragma unroll
    for (int i = 0; i < 8; i++) {
        int idx4 = i * 256 + tid;               // uint2 (4-short) units, 0..2047
        int row = idx4 >> 4, c4 = idx4 & 15;
        uint2 u = *(const uint2*)(vrow + (size_t)row * 64 + c4 * 4);
        *(uint32_t*)&lT[row * 70 + c4 * 4]     = u.x;
        *(uint32_t*)&lT[row * 70 + c4 * 4 + 2] = u.y;
    }
    __syncthreads();
    // transposed write: vhatT[bh][d][kt*128 + kc*32 .. +32]
    {
        int d = tid >> 2, kc = tid & 3;
        short* dstp = vhatT + ((size_t)bh * 64 + d) * 2048 + kt * 128 + kc * 32;
        uint32_t wd[16];
#pragma unroll
        for (int j2 = 0; j2 < 16; j2++) {
            int k0 = kc * 32 + j2 * 2;
            float v0 = bf2f(lT[k0 * 70 + d]) * lD[k0];
            float v1 = bf2f(lT[(k0 + 1) * 70 + d]) * lD[k0 + 1];
            wd[j2] = pack2bf(v0, v1);
        }
#pragma unroll
        for (int j4 = 0; j4 < 4; j4++) {
            uint4 o = {wd[j4 * 4], wd[j4 * 4 + 1], wd[j4 * 4 + 2], wd[j4 * 4 + 3]};
            *((uint4*)dstp + j4) = o;
        }
    }
}

// ---------- K4: apply; wave owns 32 q (128 q / block), split-2 over k ----------
__global__ __launch_bounds__(256, 3) void k_apply(const short* __restrict__ q_c,
                                                  const short* __restrict__ k_s,
                                                  const short* __restrict__ vhatT,
                                                  const int* __restrict__ idx,
                                                  const int* __restrict__ nU,
                                                  short* __restrict__ p0,
                                                  short* __restrict__ p1) {
    __shared__ short lK[2][4096];
    __shared__ short lV[2][4096];
    __shared__ short lP[128 * 64];              // P[q][k] bf16, chunk-XOR swizzled
    const int wg = blockIdx.x;                  // 1024 blocks
    const int x = wg & 7, r2 = wg >> 3;
    const int qt = r2 & 15, y = r2 >> 4;        // y 0..7
    const int bhsp = (y << 3) | x;              // qt-blocks of (bh,sp) share an XCD
    const int bh = bhsp >> 1, sp = bhsp & 1;
    const int b = bh >> 4, h = bh & 15;
    const int n = nU[b];
    if (qt * 128 >= n) return;                  // uniform early exit
    const int tid = threadIdx.x, w = tid >> 6, ln = tid & 63;
    const int r16 = ln & 15, g = ln >> 4;

    const short* qp = q_c + ((size_t)bh * 2048 + qt * 128 + w * 32) * 64;
    frag8 qf[2][2];
#pragma unroll
    for (int qi = 0; qi < 2; qi++)
#pragma unroll
        for (int kk = 0; kk < 2; kk++)
            qf[qi][kk] = *(const frag8*)(qp + (qi * 16 + r16) * 64 + kk * 32 + g * 8);

    const short* kp = k_s + ((size_t)bh * 2048 + sp * 1024) * 64;
    const short* vp = vhatT + (size_t)bh * 64 * 2048 + sp * 1024;

    f32x4 oacc[2][4] = {};
    const f32x4 z4 = {0.f, 0.f, 0.f, 0.f};

    stage64x128(kp, 64, &lK[0][0], tid);
    stage64x128(vp, 2048, &lV[0][0], tid);
    int buf = 0;
    for (int kb = 0; kb < 1024; kb += 64) {
        __syncthreads();
        if (kb + 64 < 1024) {
            stage64x128(kp + (size_t)(kb + 64) * 64, 64, &lK[buf ^ 1][0], tid);
            stage64x128(vp + kb + 64, 2048, &lV[buf ^ 1][0], tid);
        }
        const short* Kc = &lK[buf][0];
        const short* Vc = &lV[buf][0];
        // hoist V fragment reads (independent of QK^T chain)
        frag8 vb[4][2];
#pragma unroll
        for (int nf = 0; nf < 4; nf++)
#pragma unroll
            for (int kk = 0; kk < 2; kk++)
                vb[nf][kk] = ldswz(Vc, nf * 16 + r16, kk * 4 + g);
        // S^T (64k x 32q per wave) -> exp2 -> P[q][k]
#pragma unroll
        for (int qi = 0; qi < 2; qi++) {
            const int prow = w * 32 + qi * 16 + r16;
            const int rx = prow & 7;
#pragma unroll
            for (int mf2 = 0; mf2 < 4; mf2++) {
                f32x4 s = z4;
#pragma unroll
                for (int kk = 0; kk < 2; kk++)
                    s = MFMA16(ldswz(Kc, mf2 * 16 + r16, kk * 4 + g), qf[qi][kk], s, 0, 0, 0);
                float e0 = EXP2F(s[0]), e1 = EXP2F(s[1]);
                float e2 = EXP2F(s[2]), e3 = EXP2F(s[3]);
                uint2 pk;
                pk.x = pack2bf(e0, e1);
                pk.y = pack2bf(e2, e3);
                int o = mf2 * 32 + g * 8;       // byte offset in 128B P row
                int addr = prow * 128 + (((o >> 4) ^ rx) << 4) + (o & 15);
                *(uint2*)((char*)lP + addr) = pk;
            }
        }
        // PV: oacc[qi][d] += P[q][k] * vhat[d][k]  (same-wave P RAW: DS in-order)
#pragma unroll
        for (int qi = 0; qi < 2; qi++) {
            const int prow = w * 32 + qi * 16 + r16;
            const int rx = prow & 7;
            frag8 pa[2];
#pragma unroll
            for (int kk = 0; kk < 2; kk++)
                pa[kk] = *(const frag8*)((char*)lP + prow * 128 + (((kk * 4 + g) ^ rx) << 4));
#pragma unroll
            for (int nf = 0; nf < 4; nf++)
#pragma unroll
                for (int kk = 0; kk < 2; kk++)
                    oacc[qi][nf] = MFMA16(pa[kk], vb[nf][kk], oacc[qi][nf], 0, 0, 0);
        }
        buf ^= 1;
    }
    // epilogue: scatter unmasked rows to the split's partial buffer
    short* op = sp ? p1 : p0;
#pragma unroll
    for (int qi = 0; qi < 2; qi++)
#pragma unroll
        for (int r = 0; r < 4; r++) {
            int lq = qt * 128 + w * 32 + qi * 16 + g * 4 + r;
            if (lq < n) {
                int qg = idx[b * 2048 + lq];
#pragma unroll
                for (int nf = 0; nf < 4; nf++) {
                    int d = nf * 16 + r16;
                    op[((size_t)(b * 2048 + qg)) * 1024 + h * 64 + d] = f2bf(oacc[qi][nf][r]);
                }
            }
        }
}

// ---------- K5: out = attn @ Wo^T + b_O + Q ----------
// grid flat 256; wg%8 == tm%8 (attn-tile L2 reuse per XCD)
__global__ __launch_bounds__(256) void k_final(const short* __restrict__ A,
                                               const short* __restrict__ Bt,
                                               const float* __restrict__ bias,
                                               const float* __restrict__ Qres,
                                               float* __restrict__ out) {
    __shared__ short lA[2][4096];
    __shared__ short lB[2][4096];
    const int wg = blockIdx.x;
    const int tmb = (wg & 7) | ((wg >> 6) << 3);
    const int tnb = (wg >> 3) & 7;
    const int tid = threadIdx.x, w = tid >> 6, ln = tid & 63;
    const int wm = w >> 1, wn = w & 1, r16 = ln & 15, g = ln >> 4;
    const int tn = tnb * 128, tm = tmb * 128;
    const short* Ab = A + (size_t)tm * 1024;
    const short* Bb = Bt + (size_t)tn * 1024;

    f32x4 acc[4][4] = {};
    stage_tiles(Ab, Bb, &lA[0][0], &lB[0][0], w, ln);
    int buf = 0;
    for (int ks = 0; ks < 32; ks++) {
        __syncthreads();
        if (ks + 1 < 32)
            stage_tiles(Ab + (ks + 1) * 32, Bb + (ks + 1) * 32,
                        &lA[buf ^ 1][0], &lB[buf ^ 1][0], w, ln);
        frag8 af[4], bg[4];
#pragma unroll
        for (int mf = 0; mf < 4; mf++)
            af[mf] = *(const frag8*)&lA[buf][(wm * 64 + mf * 16 + r16) * 32 + g * 8];
#pragma unroll
        for (int nf = 0; nf < 4; nf++)
            bg[nf] = *(const frag8*)&lB[buf][(wn * 64 + nf * 16 + r16) * 32 + g * 8];
#pragma unroll
        for (int mf = 0; mf < 4; mf++)
#pragma unroll
            for (int nf = 0; nf < 4; nf++)
                acc[mf][nf] = MFMA16(af[mf], bg[nf], acc[mf][nf], 0, 0, 0);
        buf ^= 1;
    }
#pragma unroll
    for (int mf = 0; mf < 4; mf++)
#pragma unroll
        for (int nf = 0; nf < 4; nf++)
#pragma unroll
            for (int r = 0; r < 4; r++) {
                int m = tm + wm * 64 + mf * 16 + g * 4 + r;
                int n = tn + wn * 64 + nf * 16 + r16;
                float val = acc[mf][nf][r] + bias[n] + Qres[(size_t)m * 1024 + n];
                out[(size_t)m * 1024 + n] = val;
            }
}

// ---------- launch ----------
extern "C" void kernel_launch(void* const* d_in, const int* in_sizes, int n_in,
                              void* d_out, int out_size, void* d_ws, size_t ws_size,
                              hipStream_t stream) {
    (void)in_sizes; (void)n_in; (void)out_size; (void)ws_size;
    const float* Qf  = (const float*)d_in[0];
    const float* Kf  = (const float*)d_in[1];
    const float* Vf  = (const float*)d_in[2];
    const int*   msk = (const int*)d_in[3];
    const float* WQ  = (const float*)d_in[4];
    const float* bQ  = (const float*)d_in[5];
    const float* WK  = (const float*)d_in[6];
    const float* bK  = (const float*)d_in[7];
    const float* WV  = (const float*)d_in[8];
    const float* bV  = (const float*)d_in[9];
    const float* WO  = (const float*)d_in[10];
    const float* bO  = (const float*)d_in[11];
    float* out = (float*)d_out;

    char* p = (char*)d_ws;
    const size_t SZ_ACT = (size_t)4096 * 1024 * 2;  // 8 MB bf16
    const size_t SZ_W   = (size_t)1024 * 1024 * 2;  // 2 MB
    short* q_s   = (short*)p; p += SZ_ACT;
    short* k_s   = (short*)p; p += SZ_ACT;
    short* v_s   = (short*)p; p += SZ_ACT;
    short* vhatT = (short*)p; p += SZ_ACT;
    short* p0    = (short*)p; p += SZ_ACT;         // attn partial 0 / final attn
    short* q_c   = (short*)p; p += SZ_ACT;
    short* Wqb = (short*)p; p += SZ_W;
    short* Wkb = (short*)p; p += SZ_W;
    short* Wvb = (short*)p; p += SZ_W;
    short* Wob = (short*)p; p += SZ_W;
    int* idx = (int*)p; p += (size_t)2 * 2048 * 4;
    int* nU  = (int*)p; p += 256;
    short* p1 = v_s;                                // dead after k_stats

    // compaction of unmasked q indices (mask-only dependency)
    k_compact<<<2, 64, 0, stream>>>(msk, idx, nU);

    // weight converts (activations consumed fp32 by k_proj3 directly)
    k_cvt_w<<<1024, 256, 0, stream>>>(WQ, WK, WV, WO, Wqb, Wkb, Wvb, Wob);

    // fused projections (z: 0=Q scaled, 1=K, 2=V); XCD tm-grouped swizzle
    k_proj3<<<768, 256, 0, stream>>>(Qf, Kf, Vf, Wqb, Wkb, Wvb,
                                     bQ, bK, bV, q_s, k_s, v_s);

    // gather compacted Q rows
    k_gather<<<dim3(32, 32), 256, 0, stream>>>(q_s, idx, nU, q_c);

    // column softmax denominators + fused v-scale/transpose (128 k / block)
    k_stats<<<512, 256, 0, stream>>>(k_s, q_c, nU, v_s, vhatT);

    // zero both partial buffers (masked rows must be 0); v_s dead now
    k_zero2<<<2048, 256, 0, stream>>>((uint4*)p0, (uint4*)p1, 524288);

    // attention apply, 32 q / wave, split-2 over k
    k_apply<<<1024, 256, 0, stream>>>(q_c, k_s, vhatT, idx, nU, p0, p1);

    // sum partials into p0
    k_psum<<<2048, 256, 0, stream>>>(p0, p1, 524288);

    // output projection + bias + residual
    k_final<<<256, 256, 0, stream>>>(p0, Wob, bO, Qf, out);
}